// Round 19
// baseline (455.270 us; speedup 1.0000x reference)
//
#include <hip/hip_runtime.h>
#include <math.h>

#define VOCAB 500
#define EMB   64
#define HID   64
#define BB    512
#define TT    512
#define KC    8            // steps per prefetch chunk
#define NC    (TT / KC)

// tanh(x) = sign(x) * (1 - 2e/(1+e)), e = exp(-2|x|)  (stable, ~1e-6 abs err)
__device__ __forceinline__ float fast_tanh(float x) {
    float ax = fabsf(x);
    float e  = __expf(-2.0f * ax);
    float r  = __builtin_amdgcn_rcpf(1.0f + e);
    float t  = fmaf(-2.0f * e, r, 1.0f);
    return copysignf(t, x);
}

__device__ __forceinline__ float bcast(float v, int lane) {
    return __int_as_float(__builtin_amdgcn_readlane(__float_as_int(v), lane));
}

// proj[v][j] = b_ih0[j] + sum_k W_ih0[j][k] * emb[v][k]
__global__ __launch_bounds__(64) void proj_kernel(
        const float* __restrict__ emb,
        const float* __restrict__ W_ih0,
        const float* __restrict__ b_ih0,
        float* __restrict__ proj) {
    const int v = blockIdx.x;
    const int j = threadIdx.x;
    const float4* e4 = (const float4*)(emb + v * EMB);
    const float4* w4 = (const float4*)(W_ih0 + j * EMB);
    float acc = b_ih0[j];
    #pragma unroll
    for (int k = 0; k < EMB / 4; ++k) {
        float4 e = e4[k];
        float4 w = w4[k];
        acc = fmaf(w.x, e.x, acc);
        acc = fmaf(w.y, e.y, acc);
        acc = fmaf(w.z, e.z, acc);
        acc = fmaf(w.w, e.w, acc);
    }
    proj[v * HID + j] = acc;
}

// Pass 1: one wave per row, NO barriers. h1 recurrence via own-LDS float4
// broadcast (DS ops are in-order per wave). The same broadcast of h1[t-1]
// feeds BOTH W_hh0 (h1 recurrence) and W_ih1 (A[t-1] = W_ih1 . h1[t-1],
// streamed to global for pass 2).
__global__ __launch_bounds__(64, 1) void h1_kernel(
        const int*   __restrict__ x,
        const float* __restrict__ proj,
        const float* __restrict__ W_hh0,
        const float* __restrict__ b_hh0,
        const float* __restrict__ W_ih1,
        float* __restrict__ Aout) {
    const int b = blockIdx.x;
    const int j = threadIdx.x;

    __shared__ __align__(16) float hbuf[HID];
    __shared__ int xls[TT];

    for (int t = j; t < TT; t += 64) xls[t] = x[b * TT + t];

    float w0[HID], w1[HID];
    {
        const float4* a4 = (const float4*)(W_hh0 + j * HID);
        const float4* c4 = (const float4*)(W_ih1 + j * HID);
        #pragma unroll
        for (int k = 0; k < HID / 4; ++k) {
            float4 t0 = a4[k];
            w0[4*k+0] = t0.x; w0[4*k+1] = t0.y; w0[4*k+2] = t0.z; w0[4*k+3] = t0.w;
            float4 t1 = c4[k];
            w1[4*k+0] = t1.x; w1[4*k+1] = t1.y; w1[4*k+2] = t1.z; w1[4*k+3] = t1.w;
        }
    }
    #pragma unroll
    for (int k = 0; k < HID; ++k) asm volatile("" : "+v"(w0[k]), "+v"(w1[k]));

    const float bh0 = b_hh0[j];
    hbuf[j] = 0.0f;
    __syncthreads();

    float xin[KC], xinN[KC];
    #pragma unroll
    for (int u = 0; u < KC; ++u) xin[u] = proj[xls[u] * HID + j];

    float* Arow = Aout + (size_t)b * TT * HID;

    for (int c = 0; c < NC; ++c) {
        const int base = ((c + 1) & (NC - 1)) * KC;
        #pragma unroll
        for (int u = 0; u < KC; ++u)
            xinN[u] = proj[xls[base + u] * HID + j];

        #pragma unroll
        for (int u = 0; u < KC; ++u) {
            const int t = c * KC + u;
            const float4* hv = (const float4*)hbuf;   // h1[t-1]
            float a0 = xin[u] + bh0, a1 = 0.0f, a2 = 0.0f, a3 = 0.0f;
            float p0 = 0.0f, p1 = 0.0f, p2 = 0.0f, p3 = 0.0f;
            #pragma unroll
            for (int k = 0; k < HID / 4; ++k) {
                float4 h = hv[k];                     // uniform -> broadcast
                a0 = fmaf(w0[4*k+0], h.x, a0);
                a1 = fmaf(w0[4*k+1], h.y, a1);
                a2 = fmaf(w0[4*k+2], h.z, a2);
                a3 = fmaf(w0[4*k+3], h.w, a3);
                p0 = fmaf(w1[4*k+0], h.x, p0);
                p1 = fmaf(w1[4*k+1], h.y, p1);
                p2 = fmaf(w1[4*k+2], h.z, p2);
                p3 = fmaf(w1[4*k+3], h.w, p3);
            }
            const float h1n = fast_tanh((a0 + a1) + (a2 + a3));
            if (t > 0) Arow[(t - 1) * HID + j] = (p0 + p1) + (p2 + p3);
            hbuf[j] = h1n;        // DS in-order: after this iter's 16 reads
            xin[u] = xinN[u];
        }
    }
    // epilogue: A[TT-1] from h1[TT-1]
    {
        const float4* hv = (const float4*)hbuf;
        float p0 = 0.0f, p1 = 0.0f, p2 = 0.0f, p3 = 0.0f;
        #pragma unroll
        for (int k = 0; k < HID / 4; ++k) {
            float4 h = hv[k];
            p0 = fmaf(w1[4*k+0], h.x, p0);
            p1 = fmaf(w1[4*k+1], h.y, p1);
            p2 = fmaf(w1[4*k+2], h.z, p2);
            p3 = fmaf(w1[4*k+3], h.w, p3);
        }
        Arow[(TT - 1) * HID + j] = (p0 + p1) + (p2 + p3);
    }
}

// Pass 2: one wave per row, NO barriers. h2[t] = tanh(A[t] + W_hh1.h2[t-1]
// + b_ih1 + b_hh1); A read coalesced with chunk prefetch; h2 broadcast via
// own-LDS float4 reads. FC epilogue fused.
__global__ __launch_bounds__(64, 1) void h2_kernel(
        const float* __restrict__ A,
        const float* __restrict__ W_hh1,
        const float* __restrict__ b_ih1,
        const float* __restrict__ b_hh1,
        const float* __restrict__ fc_w,
        const float* __restrict__ fc_b,
        float* __restrict__ out) {
    const int b = blockIdx.x;
    const int j = threadIdx.x;

    __shared__ __align__(16) float hbuf[HID];

    float w[HID];
    {
        const float4* a4 = (const float4*)(W_hh1 + j * HID);
        #pragma unroll
        for (int k = 0; k < HID / 4; ++k) {
            float4 t0 = a4[k];
            w[4*k+0] = t0.x; w[4*k+1] = t0.y; w[4*k+2] = t0.z; w[4*k+3] = t0.w;
        }
    }
    #pragma unroll
    for (int k = 0; k < HID; ++k) asm volatile("" : "+v"(w[k]));

    const float bi1 = b_ih1[j] + b_hh1[j];
    const float fcw = fc_w[j];
    const float* Arow = A + (size_t)b * TT * HID;

    hbuf[j] = 0.0f;
    __syncthreads();

    float ain[KC], ainN[KC];
    #pragma unroll
    for (int u = 0; u < KC; ++u) ain[u] = Arow[u * HID + j];

    float h2n = 0.0f;
    for (int c = 0; c < NC; ++c) {
        const int base = ((c + 1) & (NC - 1)) * KC;
        #pragma unroll
        for (int u = 0; u < KC; ++u)
            ainN[u] = Arow[(base + u) * HID + j];

        #pragma unroll
        for (int u = 0; u < KC; ++u) {
            const float4* hv = (const float4*)hbuf;   // h2[t-1]
            float a0 = ain[u] + bi1, a1 = 0.0f, a2 = 0.0f, a3 = 0.0f;
            #pragma unroll
            for (int k = 0; k < HID / 4; ++k) {
                float4 h = hv[k];
                a0 = fmaf(w[4*k+0], h.x, a0);
                a1 = fmaf(w[4*k+1], h.y, a1);
                a2 = fmaf(w[4*k+2], h.z, a2);
                a3 = fmaf(w[4*k+3], h.w, a3);
            }
            h2n = fast_tanh((a0 + a1) + (a2 + a3));
            hbuf[j] = h2n;
            ain[u] = ainN[u];
        }
    }

    float val = h2n * fcw;
    #pragma unroll
    for (int o = 32; o > 0; o >>= 1) val += __shfl_down(val, o, 64);
    if (j == 0) out[b] = val + fc_b[0];
}

// -------- fallback (R18 kernel, used only if ws too small for A) ----------
__global__ __launch_bounds__(256, 1) void rnn_fallback(
        const int*   __restrict__ x,
        const float* __restrict__ proj,
        const float* __restrict__ W_hh0,
        const float* __restrict__ b_hh0,
        const float* __restrict__ W_ih1,
        const float* __restrict__ W_hh1,
        const float* __restrict__ b_ih1,
        const float* __restrict__ b_hh1,
        const float* __restrict__ fc_w,
        const float* __restrict__ fc_b,
        float* __restrict__ out) {
    const int b   = blockIdx.x;
    const int tid = threadIdx.x;
    const int wid = tid >> 6;
    const int j   = tid & 63;

    __shared__ __align__(16) float H1R[2][KC][HID];
    __shared__ __align__(16) float AAa[2][KC][HID];
    __shared__ __align__(16) float AAb[2][KC][HID];
    __shared__ int xls[TT];

    for (int t = tid; t < TT; t += 256) xls[t] = x[b * TT + t];

    const float* wsrc =
        (wid == 0) ? (W_hh0 + j * HID) :
        (wid == 3) ? (W_hh1 + j * HID) : (W_ih1 + j * HID);
    float w[HID];
    {
        const float4* w4 = (const float4*)wsrc;
        #pragma unroll
        for (int k = 0; k < HID / 4; ++k) {
            float4 t4 = w4[k];
            w[4*k+0] = t4.x; w[4*k+1] = t4.y; w[4*k+2] = t4.z; w[4*k+3] = t4.w;
        }
    }
    #pragma unroll
    for (int k = 0; k < HID; ++k) asm volatile("" : "+v"(w[k]));

    const float bh0 = b_hh0[j];
    const float bi1 = b_ih1[j] + b_hh1[j];
    const float fcw = fc_w[j];

    __syncthreads();

    float h1reg = 0.0f, h2reg = 0.0f;
    float xin[KC], xinN[KC];
    if (wid == 0) {
        #pragma unroll
        for (int u = 0; u < KC; ++u) xin[u] = proj[xls[u] * HID + j];
    }

    for (int c = 0; c < NC + 2; ++c) {
        if (wid == 0) {
            if (c < NC) {
                const int base = ((c + 1) & (NC - 1)) * KC;
                #pragma unroll
                for (int u = 0; u < KC; ++u)
                    xinN[u] = proj[xls[base + u] * HID + j];
                #pragma unroll
                for (int u = 0; u < KC; ++u) {
                    float a0 = xin[u] + bh0, a1 = 0.0f, a2 = 0.0f, a3 = 0.0f;
                    #pragma unroll
                    for (int k = 0; k < HID; k += 4) {
                        a0 = fmaf(w[k+0], bcast(h1reg, k+0), a0);
                        a1 = fmaf(w[k+1], bcast(h1reg, k+1), a1);
                        a2 = fmaf(w[k+2], bcast(h1reg, k+2), a2);
                        a3 = fmaf(w[k+3], bcast(h1reg, k+3), a3);
                    }
                    h1reg = fast_tanh((a0 + a1) + (a2 + a3));
                    H1R[c & 1][u][j] = h1reg;
                    xin[u] = xinN[u];
                }
            }
        } else if (wid == 1) {
            if (c >= 1 && c <= NC) {
                const int p = (c - 1) & 1;
                #pragma unroll
                for (int u = 0; u < KC; ++u) {
                    const float4* hv = (const float4*)(&H1R[p][u][0]);
                    float a0 = 0.0f, a1 = 0.0f, a2 = 0.0f, a3 = 0.0f;
                    #pragma unroll
                    for (int k = 0; k < 8; ++k) {
                        float4 h = hv[k];
                        a0 = fmaf(w[4*k+0], h.x, a0);
                        a1 = fmaf(w[4*k+1], h.y, a1);
                        a2 = fmaf(w[4*k+2], h.z, a2);
                        a3 = fmaf(w[4*k+3], h.w, a3);
                    }
                    AAa[p][u][j] = (a0 + a1) + (a2 + a3);
                }
            }
        } else if (wid == 2) {
            if (c >= 1 && c <= NC) {
                const int p = (c - 1) & 1;
                #pragma unroll
                for (int u = 0; u < KC; ++u) {
                    const float4* hv = (const float4*)(&H1R[p][u][0]);
                    float a0 = 0.0f, a1 = 0.0f, a2 = 0.0f, a3 = 0.0f;
                    #pragma unroll
                    for (int k = 8; k < 16; ++k) {
                        float4 h = hv[k];
                        a0 = fmaf(w[4*k+0], h.x, a0);
                        a1 = fmaf(w[4*k+1], h.y, a1);
                        a2 = fmaf(w[4*k+2], h.z, a2);
                        a3 = fmaf(w[4*k+3], h.w, a3);
                    }
                    AAb[p][u][j] = (a0 + a1) + (a2 + a3);
                }
            }
        } else {
            if (c >= 2) {
                const int p = c & 1;
                #pragma unroll
                for (int u = 0; u < KC; ++u) {
                    float a0 = (AAa[p][u][j] + AAb[p][u][j]) + bi1;
                    float a1 = 0.0f, a2 = 0.0f, a3 = 0.0f;
                    #pragma unroll
                    for (int k = 0; k < HID; k += 4) {
                        a0 = fmaf(w[k+0], bcast(h2reg, k+0), a0);
                        a1 = fmaf(w[k+1], bcast(h2reg, k+1), a1);
                        a2 = fmaf(w[k+2], bcast(h2reg, k+2), a2);
                        a3 = fmaf(w[k+3], bcast(h2reg, k+3), a3);
                    }
                    h2reg = fast_tanh((a0 + a1) + (a2 + a3));
                }
            }
        }
        __syncthreads();
    }

    if (wid == 3) {
        float val = h2reg * fcw;
        #pragma unroll
        for (int o = 32; o > 0; o >>= 1) val += __shfl_down(val, o, 64);
        if (j == 0) out[b] = val + fc_b[0];
    }
}

extern "C" void kernel_launch(void* const* d_in, const int* in_sizes, int n_in,
                              void* d_out, int out_size, void* d_ws, size_t ws_size,
                              hipStream_t stream) {
    const int*   x     = (const int*)  d_in[0];
    const float* emb   = (const float*)d_in[1];
    const float* W_ih0 = (const float*)d_in[2];
    const float* W_hh0 = (const float*)d_in[3];
    const float* b_ih0 = (const float*)d_in[4];
    const float* b_hh0 = (const float*)d_in[5];
    const float* W_ih1 = (const float*)d_in[6];
    const float* W_hh1 = (const float*)d_in[7];
    const float* b_ih1 = (const float*)d_in[8];
    const float* b_hh1 = (const float*)d_in[9];
    const float* fc_w  = (const float*)d_in[10];
    const float* fc_b  = (const float*)d_in[11];
    float* out  = (float*)d_out;

    float* proj = (float*)d_ws;                       // 128 KB
    const size_t projB = (size_t)VOCAB * HID * sizeof(float);
    const size_t padB  = (256 - (projB & 255)) & 255;
    float* Abuf = (float*)((char*)d_ws + projB + padB);
    const size_t needB = projB + padB + (size_t)BB * TT * HID * sizeof(float);

    proj_kernel<<<VOCAB, 64, 0, stream>>>(emb, W_ih0, b_ih0, proj);

    if (ws_size >= needB) {
        h1_kernel<<<BB, 64, 0, stream>>>(x, proj, W_hh0, b_hh0, W_ih1, Abuf);
        h2_kernel<<<BB, 64, 0, stream>>>(Abuf, W_hh1, b_ih1, b_hh1,
                                         fc_w, fc_b, out);
    } else {
        rnn_fallback<<<BB, 256, 0, stream>>>(x, proj, W_hh0, b_hh0,
                                             W_ih1, W_hh1, b_ih1, b_hh1,
                                             fc_w, fc_b, out);
    }
}